// Round 1
// baseline (2940.851 us; speedup 1.0000x reference)
//
#include <hip/hip_runtime.h>
#include <math.h>

#define EPS 1e-5f

// ---------------------------------------------------------------------------
// K1: 3x3 conv, C_in=256 -> 128-co slice, tile = one row (128 px) x 128 co.
// VARIANT 0: out = prelu(bn(acc))                         [fore]
// VARIANT 1: out = prelu(bnB(1 - prelu(bnA(acc))))        [back]
// ---------------------------------------------------------------------------
template<int VARIANT>
__global__ __launch_bounds__(256)
void conv3x3_k(const float* __restrict__ xg, const float* __restrict__ wg,
               const float* __restrict__ bnA, const float* __restrict__ aA,
               const float* __restrict__ bnB, const float* __restrict__ aB,
               float* __restrict__ outp)
{
    __shared__ __align__(16) float in_tile[8 * 3 * 132];   // [ci][row][x(-1..128)]
    __shared__ __align__(16) float w_tile[8 * 9 * 132];    // [ci*9+tap][co]

    const int t      = threadIdx.x;
    const int bid    = blockIdx.x;
    const int co_blk = bid & 1;
    const int row_id = bid >> 1;
    const int y      = row_id & 127;
    const int b      = row_id >> 7;
    const int px_base = (t & 15) * 8;
    const int co_base = (t >> 4) * 8;

    float acc[8][8];
#pragma unroll
    for (int c = 0; c < 8; ++c)
#pragma unroll
        for (int p = 0; p < 8; ++p) acc[c][p] = 0.f;

    for (int chunk = 0; chunk < 32; ++chunk) {
        const int ci_base = chunk * 8;
        // ---- stage input halo: 8 ci x 3 rows x 130 px ----
        for (int l = t; l < 3120; l += 256) {
            int ci = l / 390; int r = l - ci * 390;
            int row = r / 130; int xx = r - row * 130;
            int yin = y - 1 + row;
            int xin = xx - 1;
            float v = 0.f;
            if ((unsigned)yin < 128u && (unsigned)xin < 128u)
                v = xg[(((size_t)(b * 256 + ci_base + ci)) << 14) + (yin << 7) + xin];
            in_tile[ci * 396 + row * 132 + xx] = v;
        }
        // ---- stage weights transposed: [ci*9+tap][co], 8*9*128 ----
        for (int l = t; l < 9216; l += 256) {
            int co = l / 72; int rr = l - co * 72;
            w_tile[rr * 132 + co] =
                wg[(size_t)(co_blk * 128 + co) * 2304 + ci_base * 9 + rr];
        }
        __syncthreads();

        for (int ci = 0; ci < 8; ++ci) {
            const float* ibase = &in_tile[ci * 396];
            const float* wbase = &w_tile[ci * 9 * 132];
#pragma unroll
            for (int dy = 0; dy < 3; ++dy) {
                const float* rp = ibase + dy * 132 + px_base;
                float4 r0 = *(const float4*)rp;
                float4 r1 = *(const float4*)(rp + 4);
                float2 r2 = *(const float2*)(rp + 8);
                float rv[10] = {r0.x, r0.y, r0.z, r0.w,
                                r1.x, r1.y, r1.z, r1.w, r2.x, r2.y};
#pragma unroll
                for (int dx = 0; dx < 3; ++dx) {
                    const float* wp = wbase + (dy * 3 + dx) * 132 + co_base;
                    float4 w0 = *(const float4*)wp;
                    float4 w1 = *(const float4*)(wp + 4);
                    float wv[8] = {w0.x, w0.y, w0.z, w0.w, w1.x, w1.y, w1.z, w1.w};
#pragma unroll
                    for (int c = 0; c < 8; ++c)
#pragma unroll
                        for (int p = 0; p < 8; ++p)
                            acc[c][p] = fmaf(rv[p + dx], wv[c], acc[c][p]);
                }
            }
        }
        __syncthreads();
    }

    // ---- epilogue: BN + PReLU (+ back-branch transform) ----
    const float alA = aA[0];
    const float alB = VARIANT ? aB[0] : 0.f;
    const int row_off = y << 7;
#pragma unroll
    for (int c = 0; c < 8; ++c) {
        const int co_g = co_blk * 128 + co_base + c;
        float g  = bnA[co_g],       be = bnA[256 + co_g];
        float mm = bnA[512 + co_g], vv = bnA[768 + co_g];
        float inv = g / sqrtf(vv + EPS);
        float sh  = fmaf(-mm, inv, be);
        float invB = 0.f, shB = 0.f;
        if (VARIANT) {
            float g2  = bnB[co_g],       be2 = bnB[256 + co_g];
            float m2  = bnB[512 + co_g], v2  = bnB[768 + co_g];
            invB = g2 / sqrtf(v2 + EPS);
            shB  = fmaf(-m2, invB, be2);
        }
        float* op = outp + (((size_t)(b * 256 + co_g)) << 14) + row_off + px_base;
#pragma unroll
        for (int p = 0; p < 8; ++p) {
            float v = fmaf(acc[c][p], inv, sh);
            v = v > 0.f ? v : alA * v;
            if (VARIANT) {
                v = 1.f - v;
                v = fmaf(v, invB, shB);
                v = v > 0.f ? v : alB * v;
            }
            op[p] = v;
        }
    }
}

// ---------------------------------------------------------------------------
// K2/K4: 1x1 conv GEMM, tile = one row (128 px) x 128 co, bn+prelu epilogue.
// MODE 0: A = [fore ; back]  (K=512)   -> x12
// MODE 1: A = fore*att0 + back*att1 (fused "mid", K=256) -> out
// ---------------------------------------------------------------------------
template<int MODE>
__global__ __launch_bounds__(256)
void gemm1x1_k(const float* __restrict__ fa, const float* __restrict__ fb,
               const float* __restrict__ att0, const float* __restrict__ att1,
               const float* __restrict__ wg,
               const float* __restrict__ bn, const float* __restrict__ al,
               float* __restrict__ outp)
{
    const int K = MODE ? 256 : 512;
    __shared__ __align__(16) float a_tile[16 * 132];
    __shared__ __align__(16) float w_tile[16 * 132];

    const int t      = threadIdx.x;
    const int bid    = blockIdx.x;
    const int co_blk = bid & 1;
    const int row_id = bid >> 1;
    const int y      = row_id & 127;
    const int b      = row_id >> 7;
    const int row_off = y << 7;
    const int px_base = (t & 15) * 8;
    const int co_base = (t >> 4) * 8;

    float acc[8][8];
#pragma unroll
    for (int c = 0; c < 8; ++c)
#pragma unroll
        for (int p = 0; p < 8; ++p) acc[c][p] = 0.f;

    for (int kb = 0; kb < K; kb += 16) {
        for (int l = t; l < 2048; l += 256) {
            int kk = l >> 7, px = l & 127;
            int cg = kb + kk;
            float v;
            if (MODE == 0) {
                const float* src = (cg < 256)
                    ? fa + (((size_t)(b * 256 + cg)) << 14)
                    : fb + (((size_t)(b * 256 + cg - 256)) << 14);
                v = src[row_off + px];
            } else {
                size_t o  = (((size_t)(b * 256 + cg)) << 14) + row_off + px;
                size_t oa = ((size_t)b << 14) + row_off + px;
                v = fmaf(fa[o], att0[oa], fb[o] * att1[oa]);
            }
            a_tile[kk * 132 + px] = v;
        }
        for (int l = t; l < 2048; l += 256) {
            int co = l >> 4, kk = l & 15;
            w_tile[kk * 132 + co] = wg[(size_t)(co_blk * 128 + co) * K + kb + kk];
        }
        __syncthreads();
#pragma unroll 4
        for (int kk = 0; kk < 16; ++kk) {
            const float* ap = &a_tile[kk * 132 + px_base];
            const float* wp = &w_tile[kk * 132 + co_base];
            float4 a0 = *(const float4*)ap;       float4 a1 = *(const float4*)(ap + 4);
            float4 w0 = *(const float4*)wp;       float4 w1 = *(const float4*)(wp + 4);
            float rv[8] = {a0.x, a0.y, a0.z, a0.w, a1.x, a1.y, a1.z, a1.w};
            float wv[8] = {w0.x, w0.y, w0.z, w0.w, w1.x, w1.y, w1.z, w1.w};
#pragma unroll
            for (int c = 0; c < 8; ++c)
#pragma unroll
                for (int p = 0; p < 8; ++p)
                    acc[c][p] = fmaf(rv[p], wv[c], acc[c][p]);
        }
        __syncthreads();
    }

    const float a0s = al[0];
#pragma unroll
    for (int c = 0; c < 8; ++c) {
        const int co_g = co_blk * 128 + co_base + c;
        float g  = bn[co_g],       be = bn[256 + co_g];
        float mm = bn[512 + co_g], vv = bn[768 + co_g];
        float inv = g / sqrtf(vv + EPS);
        float sh  = fmaf(-mm, inv, be);
        float* op = outp + (((size_t)(b * 256 + co_g)) << 14) + row_off + px_base;
#pragma unroll
        for (int p = 0; p < 8; ++p) {
            float v = fmaf(acc[c][p], inv, sh);
            op[p] = v > 0.f ? v : a0s * v;
        }
    }
}

// ---------------------------------------------------------------------------
// K3: attention conv (256->2) + BN + PReLU + softmax over the 2 channels.
// One thread per pixel; coalesced channel-strided reads of x12.
// attc_bn flat layout [4][2]: g0,g1,b0,b1,m0,m1,v0,v1
// ---------------------------------------------------------------------------
__global__ __launch_bounds__(256)
void attc_k(const float* __restrict__ x12, const float* __restrict__ w2,
            const float* __restrict__ bn2, const float* __restrict__ a2,
            float* __restrict__ att0, float* __restrict__ att1)
{
    int gid = blockIdx.x * 256 + threadIdx.x;
    int b = gid >> 14; int sp = gid & 16383;
    const float* base = x12 + (((size_t)b * 256) << 14) + sp;
    float acc0 = 0.f, acc1 = 0.f;
#pragma unroll 8
    for (int c = 0; c < 256; ++c) {
        float v = base[(size_t)c << 14];
        acc0 = fmaf(w2[c], v, acc0);
        acc1 = fmaf(w2[256 + c], v, acc1);
    }
    float al = a2[0];
    float i0 = bn2[0] / sqrtf(bn2[6] + EPS);
    float s0 = fmaf(-bn2[4], i0, bn2[2]);
    float i1 = bn2[1] / sqrtf(bn2[7] + EPS);
    float s1 = fmaf(-bn2[5], i1, bn2[3]);
    float p0 = fmaf(acc0, i0, s0); p0 = p0 > 0.f ? p0 : al * p0;
    float p1 = fmaf(acc1, i1, s1); p1 = p1 > 0.f ? p1 : al * p1;
    float m = fmaxf(p0, p1);
    float e0 = expf(p0 - m), e1 = expf(p1 - m);
    float s = e0 + e1;
    att0[gid] = e0 / s;
    att1[gid] = e1 / s;
}

// ---------------------------------------------------------------------------
// K5: final 1x1 conv (256->1) + bias -> o1; then ht1 (scalar conv+bn+relu)->h0
// ---------------------------------------------------------------------------
__global__ __launch_bounds__(256)
void final_ht1_k(const float* __restrict__ outp, const float* __restrict__ wf,
                 const float* __restrict__ fbias, const float* __restrict__ w1,
                 const float* __restrict__ b1, const float* __restrict__ bn1,
                 float* __restrict__ o1, float* __restrict__ h0)
{
    int gid = blockIdx.x * 256 + threadIdx.x;
    int b = gid >> 14; int sp = gid & 16383;
    const float* base = outp + (((size_t)b * 256) << 14) + sp;
    float acc = 0.f;
#pragma unroll 8
    for (int c = 0; c < 256; ++c)
        acc = fmaf(wf[c], base[(size_t)c << 14], acc);
    acc += fbias[0];
    o1[gid] = acc;
    float t1 = fmaf(w1[0], acc, b1[0]);
    float inv = bn1[0] / sqrtf(bn1[3] + EPS);
    float sh  = fmaf(-bn1[2], inv, bn1[1]);
    float v = fmaf(t1, inv, sh);
    h0[gid] = fmaxf(v, 0.f);
}

// ---------------------------------------------------------------------------
// K6: deep Hough transform scatter. One block per (b, angle); 32 LDS bins.
// Binning in fp64 with round-half-even to bit-match numpy.
// ---------------------------------------------------------------------------
__global__ __launch_bounds__(256)
void dht_k(const float* __restrict__ h0, float* __restrict__ hacc)
{
    __shared__ double cA[128], sA[128];
    __shared__ float bins[32];
    const int t = threadIdx.x;
    const int a = blockIdx.x & 127;
    const int b = blockIdx.x >> 7;
    const double irho = 182.0 / 31.0;   // (floor(sqrt(128^2+128^2))+1)/(32-1)
    if (t < 128) {
        double th = (double)a * (M_PI / 128.0);
        cA[t] = cos(th) * (double)(t - 64);
        sA[t] = sin(th) * (double)(t - 64);
    }
    if (t < 32) bins[t] = 0.f;
    __syncthreads();
    const float* hb = h0 + ((size_t)b << 14);
    for (int i = t; i < 16384; i += 256) {
        int yy = i >> 7, xx = i & 127;
        double r = (cA[xx] + sA[yy]) / irho;
        int idx = __double2int_rn(r) + 16;
        idx = idx < 0 ? 0 : (idx > 31 ? 31 : idx);
        atomicAdd(&bins[idx], hb[i]);
    }
    __syncthreads();
    if (t < 32) hacc[(size_t)blockIdx.x * 32 + t] = bins[t];
}

// ---------------------------------------------------------------------------
// K7/K8: tiny 3x3 conv (1->1 ch) + bias + BN + ReLU on [B,1,128,32]
// ---------------------------------------------------------------------------
__global__ __launch_bounds__(256)
void htconv_k(const float* __restrict__ inp, const float* __restrict__ w9,
              const float* __restrict__ bias, const float* __restrict__ bn,
              float* __restrict__ outp)
{
    __shared__ float tile[130 * 34];
    const int t = threadIdx.x;
    const int b = blockIdx.x;
    const float* ib = inp + b * 4096;
    for (int i = t; i < 130 * 34; i += 256) {
        int ya = i / 34 - 1; int xr = i % 34 - 1;
        float v = 0.f;
        if ((unsigned)ya < 128u && (unsigned)xr < 32u) v = ib[ya * 32 + xr];
        tile[i] = v;
    }
    __syncthreads();
    float w[9];
#pragma unroll
    for (int k = 0; k < 9; ++k) w[k] = w9[k];
    const float bs = bias[0];
    const float inv = bn[0] / sqrtf(bn[3] + EPS);
    const float sh  = fmaf(-bn[2], inv, bn[1]);
    for (int i = t; i < 4096; i += 256) {
        int ya = i >> 5, xr = i & 31;
        const float* tp = &tile[ya * 34 + xr];
        float acc = bs;
#pragma unroll
        for (int ky = 0; ky < 3; ++ky)
#pragma unroll
            for (int kx = 0; kx < 3; ++kx)
                acc = fmaf(w[ky * 3 + kx], tp[ky * 34 + kx], acc);
        float v = fmaf(acc, inv, sh);
        outp[b * 4096 + i] = fmaxf(v, 0.f);
    }
}

// ---------------------------------------------------------------------------
extern "C" void kernel_launch(void* const* d_in, const int* in_sizes, int n_in,
                              void* d_out, int out_size, void* d_ws, size_t ws_size,
                              hipStream_t stream)
{
    const float* x        = (const float*)d_in[0];
    const float* conv1_w  = (const float*)d_in[1];
    const float* conv1_bn = (const float*)d_in[2];
    const float* conv1_a  = (const float*)d_in[3];
    const float* conv2_w  = (const float*)d_in[4];
    const float* conv2_bn = (const float*)d_in[5];
    const float* conv2_a  = (const float*)d_in[6];
    const float* bnr_bn   = (const float*)d_in[7];
    const float* bnr_a    = (const float*)d_in[8];
    const float* cat_w    = (const float*)d_in[9];
    const float* cat_bn   = (const float*)d_in[10];
    const float* cat_a    = (const float*)d_in[11];
    const float* attc_w   = (const float*)d_in[12];
    const float* attc_bn  = (const float*)d_in[13];
    const float* attc_a   = (const float*)d_in[14];
    const float* smooth_w = (const float*)d_in[15];
    const float* smooth_bn= (const float*)d_in[16];
    const float* smooth_a = (const float*)d_in[17];
    const float* final_w  = (const float*)d_in[18];
    const float* final_b  = (const float*)d_in[19];
    const float* ht1_w    = (const float*)d_in[20];
    const float* ht1_b    = (const float*)d_in[21];
    const float* ht1_bn   = (const float*)d_in[22];
    const float* ht2_w    = (const float*)d_in[23];
    const float* ht2_b    = (const float*)d_in[24];
    const float* ht2_bn   = (const float*)d_in[25];
    const float* ht3_w    = (const float*)d_in[26];
    const float* ht3_b    = (const float*)d_in[27];
    const float* ht3_bn   = (const float*)d_in[28];

    float* out  = (float*)d_out;                 // [4,256,128,128]
    float* o1   = out + 16777216;                // [4,1,128,128]
    float* hout = o1 + 65536;                    // [4,1,128,32]

    float* ws   = (float*)d_ws;
    float* fore = ws;                            // 16,777,216 f
    float* back = ws + 16777216;                 // 16,777,216 f
    float* x12  = ws + 2 * 16777216;             // 16,777,216 f
    float* att0 = ws + 3 * 16777216;             // 65,536 f
    float* att1 = att0 + 65536;                  // 65,536 f
    float* h0   = att1 + 65536;                  // 65,536 f
    float* hacc = h0 + 65536;                    // 16,384 f
    float* h2   = hacc + 16384;                  // 16,384 f

    conv3x3_k<0><<<1024, 256, 0, stream>>>(x, conv1_w, conv1_bn, conv1_a,
                                           nullptr, nullptr, fore);
    conv3x3_k<1><<<1024, 256, 0, stream>>>(x, conv2_w, conv2_bn, conv2_a,
                                           bnr_bn, bnr_a, back);
    gemm1x1_k<0><<<1024, 256, 0, stream>>>(fore, back, nullptr, nullptr,
                                           cat_w, cat_bn, cat_a, x12);
    attc_k<<<256, 256, 0, stream>>>(x12, attc_w, attc_bn, attc_a, att0, att1);
    gemm1x1_k<1><<<1024, 256, 0, stream>>>(fore, back, att0, att1,
                                           smooth_w, smooth_bn, smooth_a, out);
    final_ht1_k<<<256, 256, 0, stream>>>(out, final_w, final_b,
                                         ht1_w, ht1_b, ht1_bn, o1, h0);
    dht_k<<<512, 256, 0, stream>>>(h0, hacc);
    htconv_k<<<4, 256, 0, stream>>>(hacc, ht2_w, ht2_b, ht2_bn, h2);
    htconv_k<<<4, 256, 0, stream>>>(h2, ht3_w, ht3_b, ht3_bn, hout);
}

// Round 3
// 1113.026 us; speedup vs baseline: 2.6422x; 2.6422x over previous
//
#include <hip/hip_runtime.h>
#include <math.h>

#define EPS 1e-5f

typedef _Float16 half8 __attribute__((ext_vector_type(8)));
typedef float f32x4 __attribute__((ext_vector_type(4)));

__device__ __forceinline__ void gl_lds16(const void* g, void* l) {
    __builtin_amdgcn_global_load_lds((const __attribute__((address_space(1))) void*)g,
                                     (__attribute__((address_space(3))) void*)l,
                                     16, 0, 0);
}

// ---------------------------------------------------------------------------
// prep_w: W fp32 [co 256][ci 256][3][3] -> f16 hi/lo in staging order
//         wp[conv][tap 9][cc 8][co_blk 2][prec 2][co 128][ci 32]
// Also zero-fills the 4096-f16 zero-row scratch (ws is poisoned each launch).
// ---------------------------------------------------------------------------
__global__ __launch_bounds__(256)
void prep_w_k(const float* __restrict__ w1, const float* __restrict__ w2,
              _Float16* __restrict__ wp, _Float16* __restrict__ zer)
{
    int flat = blockIdx.x * 256 + threadIdx.x;      // 0 .. 1,179,647
    if (flat < 4096) zer[flat] = (_Float16)0.f;
    int conv = flat / 589824; int r = flat - conv * 589824;
    int tap = r >> 16;        int r2 = r & 65535;
    int cc = r2 >> 13;        int r3 = r2 & 8191;
    int co = r3 >> 5;         int ci = r3 & 31;
    const float* src = conv ? w2 : w1;
    float v = src[(co * 256 + cc * 32 + ci) * 9 + tap];
    _Float16 hi = (_Float16)v;
    _Float16 lo = (_Float16)(v - (float)hi);
    size_t base = (((((size_t)conv * 9 + tap) * 8 + cc) * 2 + (co >> 7)) * 2) * 4096;
    size_t off = (size_t)(co & 127) * 32 + ci;
    wp[base + off] = hi;
    wp[base + 4096 + off] = lo;
}

// ---------------------------------------------------------------------------
// prep_x: x fp32 [b][ci][y][x] -> xp[b_loc 2][y 128][cc 8][prec 2][px 128][ci 32] f16
// LDS-transposed, XOR-swizzled to tame write bank conflicts. One block per (b_loc,y).
// ---------------------------------------------------------------------------
__global__ __launch_bounds__(256)
void prep_x_k(const float* __restrict__ xg, _Float16* __restrict__ xp, int b_base)
{
    __shared__ __align__(16) _Float16 lh[128 * 72];
    __shared__ __align__(16) _Float16 ll[128 * 72];
    const int t = threadIdx.x;
    const int y = blockIdx.x & 127;
    const int b_loc = blockIdx.x >> 7;
    const int b = b_base + b_loc;
    const int px = t & 127;
    const int half_ci = t >> 7;

    for (int chunk = 0; chunk < 4; ++chunk) {       // 64 ci per chunk
        if (chunk) __syncthreads();
#pragma unroll 4
        for (int it = 0; it < 32; ++it) {
            int ci_loc = it * 2 + half_ci;
            float v = xg[(((size_t)(b * 256 + chunk * 64 + ci_loc)) << 14) + (y << 7) + px];
            _Float16 hi = (_Float16)v;
            _Float16 lo = (_Float16)(v - (float)hi);
            int col = ci_loc ^ ((px & 7) << 3);     // swizzle 8-ci groups
            lh[px * 72 + col] = hi;
            ll[px * 72 + col] = lo;
        }
        __syncthreads();
#pragma unroll
        for (int i = 0; i < 8; ++i) {
            int u = t + (i << 8);                   // 0..2047 16B-chunks
            int seg = u >> 9;                       // (ch, prec)
            int ch = seg >> 1, prec = seg & 1;
            int c2 = u & 511;
            int p2 = c2 >> 2;
            int g = ch * 4 + (c2 & 3);
            int gs = g ^ (p2 & 7);
            const _Float16* srcl = prec ? ll : lh;
            half8 v = *(const half8*)&srcl[p2 * 72 + gs * 8];
            size_t dst = ((((size_t)(b_loc * 128 + y) * 8 + (chunk * 2 + ch)) * 2 + prec) * 4096)
                       + (size_t)p2 * 32 + (c2 & 3) * 8;
            *(half8*)&xp[dst] = v;
        }
    }
}

// ---------------------------------------------------------------------------
// conv3x3_mfma: implicit-GEMM 3x3 conv via mfma_f32_16x16x32_f16, 3-pass split
// precision (~fp32 accuracy). Block = 128px (one row) x 128co, 4 waves,
// wave = 128co x 32px. LDS exactly 80 KiB -> 2 blocks/CU.
// VARIANT 0: fore = prelu(bn(acc));  VARIANT 1: back = prelu(bnB(1-prelu(bnA(acc))))
// ---------------------------------------------------------------------------
template<int VARIANT>
__global__ __launch_bounds__(256, 2)
void conv3x3_mfma(const _Float16* __restrict__ xp, const _Float16* __restrict__ wp,
                  const float* __restrict__ bnA, const float* __restrict__ aA,
                  const float* __restrict__ bnB, const float* __restrict__ aB,
                  const _Float16* __restrict__ zer,
                  float* __restrict__ outp, int b_base)
{
    // lds f16 units: [0,24576): input 2prec x 3row x 128px x 32ci
    //                [24576,40960): weights dbuf 2 x (2prec x 128co x 32ci)
    __shared__ __align__(16) _Float16 lds[40960];
    const int t = threadIdx.x;
    const int bid = blockIdx.x;
    const int co_blk = bid & 1;
    const int y = (bid >> 1) & 127;
    const int b_loc = bid >> 8;
    const int b = b_base + b_loc;
    const int l = t & 63;
    const int xq = l & 15, kg = l >> 4;
    const int xbase = (t >> 6) * 32;

    f32x4 acc[8][2];
#pragma unroll
    for (int m = 0; m < 8; ++m)
#pragma unroll
        for (int n = 0; n < 2; ++n) acc[m][n] = (f32x4){0.f, 0.f, 0.f, 0.f};

    auto stage_w = [&](int s) {
        int tap = s % 9, cc = s / 9, buf = s & 1;
        const _Float16* src = wp + (size_t)(tap * 8 + cc) * 16384 + (size_t)co_blk * 8192;
        _Float16* dst = &lds[24576 + buf * 8192];
#pragma unroll
        for (int i = 0; i < 4; ++i) {
            int u = t + (i << 8);
            gl_lds16(src + u * 8, dst + u * 8);
        }
    };
    auto stage_in = [&](int cc) {
#pragma unroll
        for (int i = 0; i < 12; ++i) {
            int u = t + (i << 8);                   // 0..3071
            int seg = u >> 9;                       // prec*3 + row
            int prec = seg >= 3 ? 1 : 0;
            int row = seg - prec * 3;
            int yin = y - 1 + row;
            const _Float16* src = ((unsigned)yin < 128u)
                ? xp + ((((size_t)(b_loc * 128 + yin) * 8 + cc) * 2 + prec) * 4096) + (u & 511) * 8
                : zer + (u & 511) * 8;
            gl_lds16(src, &lds[u * 8]);
        }
    };
    auto compute = [&](int tap, int buf) {
        const int dy = tap / 3, dx = tap % 3;
        half8 bf[2][2];
#pragma unroll
        for (int n = 0; n < 2; ++n) {
            int p = xbase + n * 16 + xq + dx - 1;
            bool valid = (unsigned)p < 128u;
            int pc = valid ? p : 0;
#pragma unroll
            for (int pr = 0; pr < 2; ++pr)
                bf[n][pr] = *(const half8*)&lds[(pr * 3 + dy) * 4096 + pc * 32 + kg * 8];
            if (!valid) {
                half8 z = {0, 0, 0, 0, 0, 0, 0, 0};
                bf[n][0] = z; bf[n][1] = z;
            }
        }
        const _Float16* wb = &lds[24576 + buf * 8192];
#pragma unroll
        for (int m = 0; m < 8; ++m) {
            int co_l = m * 16 + xq;
            half8 ahi = *(const half8*)&wb[co_l * 32 + kg * 8];
            half8 alo = *(const half8*)&wb[4096 + co_l * 32 + kg * 8];
#pragma unroll
            for (int n = 0; n < 2; ++n) {
                acc[m][n] = __builtin_amdgcn_mfma_f32_16x16x32_f16(ahi, bf[n][0], acc[m][n], 0, 0, 0);
                acc[m][n] = __builtin_amdgcn_mfma_f32_16x16x32_f16(ahi, bf[n][1], acc[m][n], 0, 0, 0);
                acc[m][n] = __builtin_amdgcn_mfma_f32_16x16x32_f16(alo, bf[n][0], acc[m][n], 0, 0, 0);
            }
        }
    };

    stage_in(0);
    stage_w(0);
    __syncthreads();
    int s = 0;
    for (int cc = 0; cc < 8; ++cc) {
#pragma unroll 1
        for (int tap = 0; tap < 9; ++tap, ++s) {
            if (s < 71) stage_w(s + 1);             // lands under compute; drained by barrier
            compute(tap, s & 1);
            __syncthreads();
            if (tap == 8 && cc < 7) { stage_in(cc + 1); __syncthreads(); }
        }
    }

    // epilogue: BN + PReLU (+ back transform). D: col(px)=lane&15, row(co)=(lane>>4)*4+r
    const float alA = aA[0];
    const float alB = VARIANT ? aB[0] : 0.f;
#pragma unroll
    for (int m = 0; m < 8; ++m) {
#pragma unroll
        for (int r = 0; r < 4; ++r) {
            int co_g = co_blk * 128 + m * 16 + kg * 4 + r;
            float g  = bnA[co_g],       be = bnA[256 + co_g];
            float mm = bnA[512 + co_g], vv = bnA[768 + co_g];
            float inv = g / sqrtf(vv + EPS);
            float sh  = fmaf(-mm, inv, be);
            float invB = 0.f, shB = 0.f;
            if (VARIANT) {
                float g2 = bnB[co_g], be2 = bnB[256 + co_g];
                float m2 = bnB[512 + co_g], v2 = bnB[768 + co_g];
                invB = g2 / sqrtf(v2 + EPS);
                shB  = fmaf(-m2, invB, be2);
            }
            float* op = outp + (((size_t)(b * 256 + co_g)) << 14) + (y << 7);
#pragma unroll
            for (int n = 0; n < 2; ++n) {
                int px = xbase + n * 16 + xq;
                float v = fmaf(acc[m][n][r], inv, sh);
                v = v > 0.f ? v : alA * v;
                if (VARIANT) {
                    v = 1.f - v;
                    v = fmaf(v, invB, shB);
                    v = v > 0.f ? v : alB * v;
                }
                op[px] = v;
            }
        }
    }
}

// ---------------------------------------------------------------------------
// K2/K4: 1x1 conv GEMM (fp32 VALU).
// MODE 0: A=[fore;back] K=512 -> x12.  MODE 1: A=fore*att0+back*att1 K=256 -> out
// ---------------------------------------------------------------------------
template<int MODE>
__global__ __launch_bounds__(256)
void gemm1x1_k(const float* __restrict__ fa, const float* __restrict__ fb,
               const float* __restrict__ att0, const float* __restrict__ att1,
               const float* __restrict__ wg,
               const float* __restrict__ bn, const float* __restrict__ al,
               float* __restrict__ outp)
{
    const int K = MODE ? 256 : 512;
    __shared__ __align__(16) float a_tile[16 * 132];
    __shared__ __align__(16) float w_tile[16 * 132];

    const int t      = threadIdx.x;
    const int bid    = blockIdx.x;
    const int co_blk = bid & 1;
    const int row_id = bid >> 1;
    const int y      = row_id & 127;
    const int b      = row_id >> 7;
    const int row_off = y << 7;
    const int px_base = (t & 15) * 8;
    const int co_base = (t >> 4) * 8;

    float acc[8][8];
#pragma unroll
    for (int c = 0; c < 8; ++c)
#pragma unroll
        for (int p = 0; p < 8; ++p) acc[c][p] = 0.f;

    for (int kb = 0; kb < K; kb += 16) {
        for (int lx = t; lx < 2048; lx += 256) {
            int kk = lx >> 7, px = lx & 127;
            int cg = kb + kk;
            float v;
            if (MODE == 0) {
                const float* src = (cg < 256)
                    ? fa + (((size_t)(b * 256 + cg)) << 14)
                    : fb + (((size_t)(b * 256 + cg - 256)) << 14);
                v = src[row_off + px];
            } else {
                size_t o  = (((size_t)(b * 256 + cg)) << 14) + row_off + px;
                size_t oa = ((size_t)b << 14) + row_off + px;
                v = fmaf(fa[o], att0[oa], fb[o] * att1[oa]);
            }
            a_tile[kk * 132 + px] = v;
        }
        for (int lx = t; lx < 2048; lx += 256) {
            int co = lx >> 4, kk = lx & 15;
            w_tile[kk * 132 + co] = wg[(size_t)(co_blk * 128 + co) * K + kb + kk];
        }
        __syncthreads();
#pragma unroll 4
        for (int kk = 0; kk < 16; ++kk) {
            const float* ap = &a_tile[kk * 132 + px_base];
            const float* wpp = &w_tile[kk * 132 + co_base];
            float4 a0 = *(const float4*)ap;       float4 a1 = *(const float4*)(ap + 4);
            float4 w0 = *(const float4*)wpp;      float4 w1 = *(const float4*)(wpp + 4);
            float rv[8] = {a0.x, a0.y, a0.z, a0.w, a1.x, a1.y, a1.z, a1.w};
            float wv[8] = {w0.x, w0.y, w0.z, w0.w, w1.x, w1.y, w1.z, w1.w};
#pragma unroll
            for (int c = 0; c < 8; ++c)
#pragma unroll
                for (int p = 0; p < 8; ++p)
                    acc[c][p] = fmaf(rv[p], wv[c], acc[c][p]);
        }
        __syncthreads();
    }

    const float a0s = al[0];
#pragma unroll
    for (int c = 0; c < 8; ++c) {
        const int co_g = co_blk * 128 + co_base + c;
        float g  = bn[co_g],       be = bn[256 + co_g];
        float mm = bn[512 + co_g], vv = bn[768 + co_g];
        float inv = g / sqrtf(vv + EPS);
        float sh  = fmaf(-mm, inv, be);
        float* op = outp + (((size_t)(b * 256 + co_g)) << 14) + row_off + px_base;
#pragma unroll
        for (int p = 0; p < 8; ++p) {
            float v = fmaf(acc[c][p], inv, sh);
            op[p] = v > 0.f ? v : a0s * v;
        }
    }
}

// ---------------------------------------------------------------------------
__global__ __launch_bounds__(256)
void attc_k(const float* __restrict__ x12, const float* __restrict__ w2,
            const float* __restrict__ bn2, const float* __restrict__ a2,
            float* __restrict__ att0, float* __restrict__ att1)
{
    int gid = blockIdx.x * 256 + threadIdx.x;
    int b = gid >> 14; int sp = gid & 16383;
    const float* base = x12 + (((size_t)b * 256) << 14) + sp;
    float acc0 = 0.f, acc1 = 0.f;
#pragma unroll 8
    for (int c = 0; c < 256; ++c) {
        float v = base[(size_t)c << 14];
        acc0 = fmaf(w2[c], v, acc0);
        acc1 = fmaf(w2[256 + c], v, acc1);
    }
    float al = a2[0];
    float i0 = bn2[0] / sqrtf(bn2[6] + EPS);
    float s0 = fmaf(-bn2[4], i0, bn2[2]);
    float i1 = bn2[1] / sqrtf(bn2[7] + EPS);
    float s1 = fmaf(-bn2[5], i1, bn2[3]);
    float p0 = fmaf(acc0, i0, s0); p0 = p0 > 0.f ? p0 : al * p0;
    float p1 = fmaf(acc1, i1, s1); p1 = p1 > 0.f ? p1 : al * p1;
    float m = fmaxf(p0, p1);
    float e0 = expf(p0 - m), e1 = expf(p1 - m);
    float s = e0 + e1;
    att0[gid] = e0 / s;
    att1[gid] = e1 / s;
}

// ---------------------------------------------------------------------------
__global__ __launch_bounds__(256)
void final_ht1_k(const float* __restrict__ outp, const float* __restrict__ wf,
                 const float* __restrict__ fbias, const float* __restrict__ w1,
                 const float* __restrict__ b1, const float* __restrict__ bn1,
                 float* __restrict__ o1, float* __restrict__ h0)
{
    int gid = blockIdx.x * 256 + threadIdx.x;
    int b = gid >> 14; int sp = gid & 16383;
    const float* base = outp + (((size_t)b * 256) << 14) + sp;
    float acc = 0.f;
#pragma unroll 8
    for (int c = 0; c < 256; ++c)
        acc = fmaf(wf[c], base[(size_t)c << 14], acc);
    acc += fbias[0];
    o1[gid] = acc;
    float t1 = fmaf(w1[0], acc, b1[0]);
    float inv = bn1[0] / sqrtf(bn1[3] + EPS);
    float sh  = fmaf(-bn1[2], inv, bn1[1]);
    float v = fmaf(t1, inv, sh);
    h0[gid] = fmaxf(v, 0.f);
}

// ---------------------------------------------------------------------------
__global__ __launch_bounds__(256)
void dht_k(const float* __restrict__ h0, float* __restrict__ hacc)
{
    __shared__ double cA[128], sA[128];
    __shared__ float bins[32];
    const int t = threadIdx.x;
    const int a = blockIdx.x & 127;
    const int b = blockIdx.x >> 7;
    const double irho = 182.0 / 31.0;
    if (t < 128) {
        double th = (double)a * (M_PI / 128.0);
        cA[t] = cos(th) * (double)(t - 64);
        sA[t] = sin(th) * (double)(t - 64);
    }
    if (t < 32) bins[t] = 0.f;
    __syncthreads();
    const float* hb = h0 + ((size_t)b << 14);
    for (int i = t; i < 16384; i += 256) {
        int yy = i >> 7, xx = i & 127;
        double r = (cA[xx] + sA[yy]) / irho;
        int idx = __double2int_rn(r) + 16;
        idx = idx < 0 ? 0 : (idx > 31 ? 31 : idx);
        atomicAdd(&bins[idx], hb[i]);
    }
    __syncthreads();
    if (t < 32) hacc[(size_t)blockIdx.x * 32 + t] = bins[t];
}

// ---------------------------------------------------------------------------
__global__ __launch_bounds__(256)
void htconv_k(const float* __restrict__ inp, const float* __restrict__ w9,
              const float* __restrict__ bias, const float* __restrict__ bn,
              float* __restrict__ outp)
{
    __shared__ float tile[130 * 34];
    const int t = threadIdx.x;
    const int b = blockIdx.x;
    const float* ib = inp + b * 4096;
    for (int i = t; i < 130 * 34; i += 256) {
        int ya = i / 34 - 1; int xr = i % 34 - 1;
        float v = 0.f;
        if ((unsigned)ya < 128u && (unsigned)xr < 32u) v = ib[ya * 32 + xr];
        tile[i] = v;
    }
    __syncthreads();
    float w[9];
#pragma unroll
    for (int k = 0; k < 9; ++k) w[k] = w9[k];
    const float bs = bias[0];
    const float inv = bn[0] / sqrtf(bn[3] + EPS);
    const float sh  = fmaf(-bn[2], inv, bn[1]);
    for (int i = t; i < 4096; i += 256) {
        int ya = i >> 5, xr = i & 31;
        const float* tp = &tile[ya * 34 + xr];
        float acc = bs;
#pragma unroll
        for (int ky = 0; ky < 3; ++ky)
#pragma unroll
            for (int kx = 0; kx < 3; ++kx)
                acc = fmaf(w[ky * 3 + kx], tp[ky * 34 + kx], acc);
        float v = fmaf(acc, inv, sh);
        outp[b * 4096 + i] = fmaxf(v, 0.f);
    }
}

// ---------------------------------------------------------------------------
extern "C" void kernel_launch(void* const* d_in, const int* in_sizes, int n_in,
                              void* d_out, int out_size, void* d_ws, size_t ws_size,
                              hipStream_t stream)
{
    const float* x        = (const float*)d_in[0];
    const float* conv1_w  = (const float*)d_in[1];
    const float* conv1_bn = (const float*)d_in[2];
    const float* conv1_a  = (const float*)d_in[3];
    const float* conv2_w  = (const float*)d_in[4];
    const float* conv2_bn = (const float*)d_in[5];
    const float* conv2_a  = (const float*)d_in[6];
    const float* bnr_bn   = (const float*)d_in[7];
    const float* bnr_a    = (const float*)d_in[8];
    const float* cat_w    = (const float*)d_in[9];
    const float* cat_bn   = (const float*)d_in[10];
    const float* cat_a    = (const float*)d_in[11];
    const float* attc_w   = (const float*)d_in[12];
    const float* attc_bn  = (const float*)d_in[13];
    const float* attc_a   = (const float*)d_in[14];
    const float* smooth_w = (const float*)d_in[15];
    const float* smooth_bn= (const float*)d_in[16];
    const float* smooth_a = (const float*)d_in[17];
    const float* final_w  = (const float*)d_in[18];
    const float* final_b  = (const float*)d_in[19];
    const float* ht1_w    = (const float*)d_in[20];
    const float* ht1_b    = (const float*)d_in[21];
    const float* ht1_bn   = (const float*)d_in[22];
    const float* ht2_w    = (const float*)d_in[23];
    const float* ht2_b    = (const float*)d_in[24];
    const float* ht2_bn   = (const float*)d_in[25];
    const float* ht3_w    = (const float*)d_in[26];
    const float* ht3_b    = (const float*)d_in[27];
    const float* ht3_bn   = (const float*)d_in[28];

    float* out  = (float*)d_out;                 // [4,256,128,128]
    float* o1   = out + 16777216;                // [4,1,128,128]
    float* hout = o1 + 65536;                    // [4,1,128,32]

    float* ws   = (float*)d_ws;
    float* fore = ws;                            // 16,777,216 f
    float* back = ws + 16777216;                 // 16,777,216 f
    float* x12  = ws + 2 * 16777216;             // 16,777,216 f (alive post-conv only)
    float* att0 = ws + 3 * 16777216;
    float* att1 = att0 + 65536;
    float* h0   = att1 + 65536;
    float* hacc = h0 + 65536;
    float* h2   = hacc + 16384;

    // conv-phase scratch aliased into x12's region (dead until gemm1x1<0>):
    _Float16* xp  = (_Float16*)(ws + 2 * 16777216);              // 16,777,216 f16 (half-batch)
    _Float16* wpq = (_Float16*)(ws + 2 * 16777216 + 8388608);    // 1,179,648 f16
    _Float16* zer = (_Float16*)(ws + 2 * 16777216 + 8388608 + 1179648); // 4096 f16
    const size_t WPC = (size_t)9 * 8 * 2 * 2 * 4096;             // per-conv wp stride

    prep_w_k<<<4608, 256, 0, stream>>>(conv1_w, conv2_w, wpq, zer);
    for (int half = 0; half < 2; ++half) {
        prep_x_k<<<256, 256, 0, stream>>>(x, xp, half * 2);
        conv3x3_mfma<0><<<512, 256, 0, stream>>>(xp, wpq, conv1_bn, conv1_a,
                                                 nullptr, nullptr, zer, fore, half * 2);
        conv3x3_mfma<1><<<512, 256, 0, stream>>>(xp, wpq + WPC, conv2_bn, conv2_a,
                                                 bnr_bn, bnr_a, zer, back, half * 2);
    }
    gemm1x1_k<0><<<1024, 256, 0, stream>>>(fore, back, nullptr, nullptr,
                                           cat_w, cat_bn, cat_a, x12);
    attc_k<<<256, 256, 0, stream>>>(x12, attc_w, attc_bn, attc_a, att0, att1);
    gemm1x1_k<1><<<1024, 256, 0, stream>>>(fore, back, att0, att1,
                                           smooth_w, smooth_bn, smooth_a, out);
    final_ht1_k<<<256, 256, 0, stream>>>(out, final_w, final_b,
                                         ht1_w, ht1_b, ht1_bn, o1, h0);
    dht_k<<<512, 256, 0, stream>>>(h0, hacc);
    htconv_k<<<4, 256, 0, stream>>>(hacc, ht2_w, ht2_b, ht2_bn, h2);
    htconv_k<<<4, 256, 0, stream>>>(h2, ht3_w, ht3_b, ht3_bn, hout);
}

// Round 7
// 882.838 us; speedup vs baseline: 3.3311x; 1.2607x over previous
//
#include <hip/hip_runtime.h>
#include <math.h>

#define EPS 1e-5f

typedef _Float16 half8 __attribute__((ext_vector_type(8)));
typedef float f32x4 __attribute__((ext_vector_type(4)));

__device__ __forceinline__ void gl_lds16(const void* g, void* l) {
    __builtin_amdgcn_global_load_lds((const __attribute__((address_space(1))) void*)g,
                                     (__attribute__((address_space(3))) void*)l,
                                     16, 0, 0);
}

// ---------------------------------------------------------------------------
// prep_w: W fp32 [co 256][ci 256][3][3] -> f16 hi/lo in staging order
//         wp[conv][tap 9][cc 8][co_blk 2][prec 2][co 128][ci 32]
// ci-chunk position swizzled: pos s holds data chunk s ^ ((co>>1)&3)
// Also zero-fills the 4096-f16 zero-row scratch.
// ---------------------------------------------------------------------------
__global__ __launch_bounds__(256)
void prep_w_k(const float* __restrict__ w1, const float* __restrict__ w2,
              _Float16* __restrict__ wp, _Float16* __restrict__ zer)
{
    int flat = blockIdx.x * 256 + threadIdx.x;      // 0 .. 1,179,647
    if (flat < 4096) zer[flat] = (_Float16)0.f;
    int conv = flat / 589824; int r = flat - conv * 589824;
    int tap = r >> 16;        int r2 = r & 65535;
    int cc = r2 >> 13;        int r3 = r2 & 8191;
    int co = r3 >> 5;         int ci = r3 & 31;
    const float* src = conv ? w2 : w1;
    float v = src[(co * 256 + cc * 32 + ci) * 9 + tap];
    _Float16 hi = (_Float16)v;
    _Float16 lo = (_Float16)(v - (float)hi);
    size_t base = (((((size_t)conv * 9 + tap) * 8 + cc) * 2 + (co >> 7)) * 2) * 4096;
    int col = co & 127;
    size_t off = (size_t)col * 32 + (((ci >> 3) ^ ((col >> 1) & 3)) << 3) + (ci & 7);
    wp[base + off] = hi;
    wp[base + 4096 + off] = lo;
}

// ---------------------------------------------------------------------------
// prep_w1x1: 1x1 weights fp32 [256 co][K ci] -> wp[co_blk][kstep][prec][co 128][ci 32]
// same ci-chunk swizzle keyed on (co>>1)&3.
// ---------------------------------------------------------------------------
__global__ __launch_bounds__(256)
void prep_w1x1_k(const float* __restrict__ wg, _Float16* __restrict__ wp, int K)
{
    int e = blockIdx.x * 256 + threadIdx.x;
    if (e >= 256 * K) return;
    int co = e / K, ci = e - co * K;
    float v = wg[e];
    _Float16 hi = (_Float16)v;
    _Float16 lo = (_Float16)(v - (float)hi);
    int kstep = ci >> 5, ci32 = ci & 31;
    int col = co & 127;
    int s = (ci32 >> 3) ^ ((col >> 1) & 3);
    size_t base = (((size_t)(co >> 7) * (K >> 5) + kstep) * 2) * 4096;
    size_t off = (size_t)col * 32 + (s << 3) + (ci32 & 7);
    wp[base + off] = hi;
    wp[base + 4096 + off] = lo;
}

// ---------------------------------------------------------------------------
// prep_x: x fp32 [b][ci][y][x] -> xp[b_loc 2][y 128][cc 8][prec 2][px 128][ci 32] f16
// ci-chunk position s holds data chunk s ^ ((px>>1)&3) (matches conv read swizzle).
// ---------------------------------------------------------------------------
__global__ __launch_bounds__(256)
void prep_x_k(const float* __restrict__ xg, _Float16* __restrict__ xp, int b_base)
{
    __shared__ __align__(16) _Float16 lh[128 * 72];
    __shared__ __align__(16) _Float16 ll[128 * 72];
    const int t = threadIdx.x;
    const int y = blockIdx.x & 127;
    const int b_loc = blockIdx.x >> 7;
    const int b = b_base + b_loc;
    const int px = t & 127;
    const int half_ci = t >> 7;

    for (int chunk = 0; chunk < 4; ++chunk) {       // 64 ci per chunk
        if (chunk) __syncthreads();
#pragma unroll 4
        for (int it = 0; it < 32; ++it) {
            int ci_loc = it * 2 + half_ci;
            float v = xg[(((size_t)(b * 256 + chunk * 64 + ci_loc)) << 14) + (y << 7) + px];
            _Float16 hi = (_Float16)v;
            _Float16 lo = (_Float16)(v - (float)hi);
            int col = ci_loc ^ ((px & 7) << 3);     // internal 8-group swizzle
            lh[px * 72 + col] = hi;
            ll[px * 72 + col] = lo;
        }
        __syncthreads();
#pragma unroll
        for (int i = 0; i < 8; ++i) {
            int u = t + (i << 8);                   // 0..2047 16B-chunks
            int seg = u >> 9;                       // (ch, prec)
            int ch = seg >> 1, prec = seg & 1;
            int c2 = u & 511;
            int p2 = c2 >> 2;                       // px
            int g = ch * 4 + ((c2 & 3) ^ ((p2 >> 1) & 3));  // data 8-group for pos c2&3
            int gs = g ^ (p2 & 7);
            const _Float16* srcl = prec ? ll : lh;
            half8 v = *(const half8*)&srcl[p2 * 72 + gs * 8];
            size_t dst = ((((size_t)(b_loc * 128 + y) * 8 + (chunk * 2 + ch)) * 2 + prec) * 4096)
                       + (size_t)p2 * 32 + (c2 & 3) * 8;
            *(half8*)&xp[dst] = v;
        }
    }
}

// ---------------------------------------------------------------------------
// conv3x3_mfma: implicit-GEMM 3x3 conv via mfma_f32_16x16x32_f16, 3-pass split
// precision. Block = 128px (one row) x 128co, 4 waves, wave = 128co x 32px.
// Fragment reads use the (row>>1)&3 chunk swizzle -> LDS bank-quad floor.
// ---------------------------------------------------------------------------
template<int VARIANT>
__global__ __launch_bounds__(256, 2)
void conv3x3_mfma(const _Float16* __restrict__ xp, const _Float16* __restrict__ wp,
                  const float* __restrict__ bnA, const float* __restrict__ aA,
                  const float* __restrict__ bnB, const float* __restrict__ aB,
                  const _Float16* __restrict__ zer,
                  float* __restrict__ outp, int b_base)
{
    // lds f16 units: [0,24576): input 2prec x 3row x 128px x 32ci
    //                [24576,40960): weights dbuf 2 x (2prec x 128co x 32ci)
    __shared__ __align__(16) _Float16 lds[40960];
    const int t = threadIdx.x;
    const int bid = blockIdx.x;
    const int co_blk = bid & 1;
    const int y = (bid >> 1) & 127;
    const int b_loc = bid >> 8;
    const int b = b_base + b_loc;
    const int l = t & 63;
    const int xq = l & 15, kg = l >> 4;
    const int xbase = (t >> 6) * 32;

    f32x4 acc[8][2];
#pragma unroll
    for (int m = 0; m < 8; ++m)
#pragma unroll
        for (int n = 0; n < 2; ++n) acc[m][n] = (f32x4){0.f, 0.f, 0.f, 0.f};

    auto stage_w = [&](int s) {
        int tap = s % 9, cc = s / 9, buf = s & 1;
        const _Float16* src = wp + (size_t)(tap * 8 + cc) * 16384 + (size_t)co_blk * 8192;
        _Float16* dst = &lds[24576 + buf * 8192];
#pragma unroll
        for (int i = 0; i < 4; ++i) {
            int u = t + (i << 8);
            gl_lds16(src + u * 8, dst + u * 8);
        }
    };
    auto stage_in = [&](int cc) {
#pragma unroll
        for (int i = 0; i < 12; ++i) {
            int u = t + (i << 8);                   // 0..3071
            int seg = u >> 9;                       // prec*3 + row
            int prec = seg >= 3 ? 1 : 0;
            int row = seg - prec * 3;
            int yin = y - 1 + row;
            const _Float16* src = ((unsigned)yin < 128u)
                ? xp + ((((size_t)(b_loc * 128 + yin) * 8 + cc) * 2 + prec) * 4096) + (u & 511) * 8
                : zer + (u & 511) * 8;
            gl_lds16(src, &lds[u * 8]);
        }
    };
    auto compute = [&](int tap, int buf) {
        const int dy = tap / 3, dx = tap % 3;
        half8 bf[2][2];
#pragma unroll
        for (int n = 0; n < 2; ++n) {
            int p = xbase + n * 16 + xq + dx - 1;
            bool valid = (unsigned)p < 128u;
            int pc = valid ? p : 0;
            int coff = pc * 32 + ((kg ^ ((pc >> 1) & 3)) << 3);
#pragma unroll
            for (int pr = 0; pr < 2; ++pr)
                bf[n][pr] = *(const half8*)&lds[(pr * 3 + dy) * 4096 + coff];
            if (!valid) {
                half8 z = {0, 0, 0, 0, 0, 0, 0, 0};
                bf[n][0] = z; bf[n][1] = z;
            }
        }
        const _Float16* wb = &lds[24576 + buf * 8192];
#pragma unroll
        for (int m = 0; m < 8; ++m) {
            int co_l = m * 16 + xq;
            int woff = co_l * 32 + ((kg ^ ((co_l >> 1) & 3)) << 3);
            half8 ahi = *(const half8*)&wb[woff];
            half8 alo = *(const half8*)&wb[4096 + woff];
#pragma unroll
            for (int n = 0; n < 2; ++n) {
                acc[m][n] = __builtin_amdgcn_mfma_f32_16x16x32_f16(ahi, bf[n][0], acc[m][n], 0, 0, 0);
                acc[m][n] = __builtin_amdgcn_mfma_f32_16x16x32_f16(ahi, bf[n][1], acc[m][n], 0, 0, 0);
                acc[m][n] = __builtin_amdgcn_mfma_f32_16x16x32_f16(alo, bf[n][0], acc[m][n], 0, 0, 0);
            }
        }
    };

    stage_in(0);
    stage_w(0);
    __syncthreads();
    int s = 0;
    for (int cc = 0; cc < 8; ++cc) {
#pragma unroll 1
        for (int tap = 0; tap < 9; ++tap, ++s) {
            if (s < 71) stage_w(s + 1);
            compute(tap, s & 1);
            __syncthreads();
            if (tap == 8 && cc < 7) { stage_in(cc + 1); __syncthreads(); }
        }
    }

    // epilogue: BN + PReLU (+ back transform). D: col(px)=lane&15, row(co)=(lane>>4)*4+r
    const float alA = aA[0];
    const float alB = VARIANT ? aB[0] : 0.f;
#pragma unroll
    for (int m = 0; m < 8; ++m) {
#pragma unroll
        for (int r = 0; r < 4; ++r) {
            int co_g = co_blk * 128 + m * 16 + kg * 4 + r;
            float g  = bnA[co_g],       be = bnA[256 + co_g];
            float mm = bnA[512 + co_g], vv = bnA[768 + co_g];
            float inv = g / sqrtf(vv + EPS);
            float sh  = fmaf(-mm, inv, be);
            float invB = 0.f, shB = 0.f;
            if (VARIANT) {
                float g2 = bnB[co_g], be2 = bnB[256 + co_g];
                float m2 = bnB[512 + co_g], v2 = bnB[768 + co_g];
                invB = g2 / sqrtf(v2 + EPS);
                shB  = fmaf(-m2, invB, be2);
            }
            float* op = outp + (((size_t)(b * 256 + co_g)) << 14) + (y << 7);
#pragma unroll
            for (int n = 0; n < 2; ++n) {
                int px = xbase + n * 16 + xq;
                float v = fmaf(acc[m][n][r], inv, sh);
                v = v > 0.f ? v : alA * v;
                if (VARIANT) {
                    v = 1.f - v;
                    v = fmaf(v, invB, shB);
                    v = v > 0.f ? v : alB * v;
                }
                op[px] = v;
            }
        }
    }
}

// ---------------------------------------------------------------------------
// gemm1x1_mfma: 1x1 conv via mfma_f32_16x16x32_f16, 3-pass split precision.
// Block = 128px (one y-row) x 128co, 4 waves. A staged via VALU f32->hi/lo
// split + swizzled ds_write; W via global_load_lds from pre-split layout.
// MODE 0: A=[fore;back] K=512 -> x12 = prelu(bn(cat_w . A))
// MODE 1: A=fore*att0+back*att1 K=256 -> out = prelu(bn(smooth_w . A))
// ---------------------------------------------------------------------------
template<int MODE>
__global__ __launch_bounds__(256, 2)
void gemm1x1_mfma(const float* __restrict__ fa, const float* __restrict__ fb,
                  const float* __restrict__ att0, const float* __restrict__ att1,
                  const _Float16* __restrict__ wp,
                  const float* __restrict__ bn, const float* __restrict__ al,
                  float* __restrict__ outp)
{
    const int KSTEPS = MODE ? 8 : 16;
    // lds: A [2buf][2prec][128px][32ci] @0 (16384), W same @16384
    __shared__ __align__(16) _Float16 lds[32768];
    __shared__ float attb[2][128];
    const int t = threadIdx.x;
    const int bid = blockIdx.x;
    const int co_blk = bid & 1;
    const int y = (bid >> 1) & 127;
    const int b = bid >> 8;
    const int l = t & 63;
    const int xq = l & 15, kg = l >> 4;
    const int xbase = (t >> 6) * 32;
    const int px_s = t & 127;                       // staging px
    const int qh = (t >> 7) * 2;                    // staging first ci-chunk

    f32x4 acc[8][2];
#pragma unroll
    for (int m = 0; m < 8; ++m)
#pragma unroll
        for (int n = 0; n < 2; ++n) acc[m][n] = (f32x4){0.f, 0.f, 0.f, 0.f};

    if (MODE) {
        if (t < 128) {
            attb[0][t] = att0[((size_t)b << 14) + (y << 7) + t];
            attb[1][t] = att1[((size_t)b << 14) + (y << 7) + t];
        }
        __syncthreads();
    }

    auto stage_w = [&](int s) {
        const _Float16* src = wp + (size_t)(co_blk * KSTEPS + s) * 8192;
        _Float16* dst = &lds[16384 + (s & 1) * 8192];
#pragma unroll
        for (int i = 0; i < 4; ++i) {
            int u = t + (i << 8);
            gl_lds16(src + u * 8, dst + u * 8);
        }
    };
    auto stage_a = [&](int s) {
        const int buf = s & 1;
        const float* srcA = fa; int ch = s * 32;
        if (MODE == 0 && s >= 8) { srcA = fb; ch = s * 32 - 256; }
        float a0 = 0.f, a1 = 0.f;
        if (MODE) { a0 = attb[0][px_s]; a1 = attb[1][px_s]; }
#pragma unroll
        for (int task = 0; task < 2; ++task) {
            int q = qh + task;
            int ci0 = q * 8;
            half8 hi, lo;
#pragma unroll
            for (int j = 0; j < 8; ++j) {
                size_t o = (((size_t)(b * 256 + ch + ci0 + j)) << 14) + (y << 7) + px_s;
                float v;
                if (MODE == 0) v = srcA[o];
                else           v = fmaf(fa[o], a0, fb[o] * a1);
                _Float16 h = (_Float16)v;
                hi[j] = h;
                lo[j] = (_Float16)(v - (float)h);
            }
            int sp = q ^ ((px_s >> 1) & 3);
            *(half8*)&lds[buf * 8192 + px_s * 32 + sp * 8] = hi;
            *(half8*)&lds[buf * 8192 + 4096 + px_s * 32 + sp * 8] = lo;
        }
    };
    auto compute = [&](int s) {
        const int buf = s & 1;
        const _Float16* xb = &lds[buf * 8192];
        const _Float16* wb = &lds[16384 + buf * 8192];
        half8 bhi[2], blo[2];
#pragma unroll
        for (int n = 0; n < 2; ++n) {
            int px = xbase + n * 16 + xq;
            int off = px * 32 + ((kg ^ ((px >> 1) & 3)) << 3);
            bhi[n] = *(const half8*)&xb[off];
            blo[n] = *(const half8*)&xb[4096 + off];
        }
#pragma unroll
        for (int m = 0; m < 8; ++m) {
            int co_l = m * 16 + xq;
            int woff = co_l * 32 + ((kg ^ ((co_l >> 1) & 3)) << 3);
            half8 ahi = *(const half8*)&wb[woff];
            half8 alo = *(const half8*)&wb[4096 + woff];
#pragma unroll
            for (int n = 0; n < 2; ++n) {
                acc[m][n] = __builtin_amdgcn_mfma_f32_16x16x32_f16(ahi, bhi[n], acc[m][n], 0, 0, 0);
                acc[m][n] = __builtin_amdgcn_mfma_f32_16x16x32_f16(ahi, blo[n], acc[m][n], 0, 0, 0);
                acc[m][n] = __builtin_amdgcn_mfma_f32_16x16x32_f16(alo, bhi[n], acc[m][n], 0, 0, 0);
            }
        }
    };

    stage_a(0);
    stage_w(0);
    __syncthreads();
#pragma unroll 1
    for (int s = 0; s < KSTEPS; ++s) {
        if (s + 1 < KSTEPS) { stage_a(s + 1); stage_w(s + 1); }
        compute(s);
        __syncthreads();
    }

    const float a0s = al[0];
#pragma unroll
    for (int m = 0; m < 8; ++m) {
#pragma unroll
        for (int r = 0; r < 4; ++r) {
            int co_g = co_blk * 128 + m * 16 + kg * 4 + r;
            float g  = bn[co_g],       be = bn[256 + co_g];
            float mm = bn[512 + co_g], vv = bn[768 + co_g];
            float inv = g / sqrtf(vv + EPS);
            float sh  = fmaf(-mm, inv, be);
            float* op = outp + (((size_t)(b * 256 + co_g)) << 14) + (y << 7);
#pragma unroll
            for (int n = 0; n < 2; ++n) {
                int px = xbase + n * 16 + xq;
                float v = fmaf(acc[m][n][r], inv, sh);
                op[px] = v > 0.f ? v : a0s * v;
            }
        }
    }
}

// ---------------------------------------------------------------------------
__global__ __launch_bounds__(256)
void attc_k(const float* __restrict__ x12, const float* __restrict__ w2,
            const float* __restrict__ bn2, const float* __restrict__ a2,
            float* __restrict__ att0, float* __restrict__ att1)
{
    int gid = blockIdx.x * 256 + threadIdx.x;
    int b = gid >> 14; int sp = gid & 16383;
    const float* base = x12 + (((size_t)b * 256) << 14) + sp;
    float acc0 = 0.f, acc1 = 0.f;
#pragma unroll 8
    for (int c = 0; c < 256; ++c) {
        float v = base[(size_t)c << 14];
        acc0 = fmaf(w2[c], v, acc0);
        acc1 = fmaf(w2[256 + c], v, acc1);
    }
    float al = a2[0];
    float i0 = bn2[0] / sqrtf(bn2[6] + EPS);
    float s0 = fmaf(-bn2[4], i0, bn2[2]);
    float i1 = bn2[1] / sqrtf(bn2[7] + EPS);
    float s1 = fmaf(-bn2[5], i1, bn2[3]);
    float p0 = fmaf(acc0, i0, s0); p0 = p0 > 0.f ? p0 : al * p0;
    float p1 = fmaf(acc1, i1, s1); p1 = p1 > 0.f ? p1 : al * p1;
    float m = fmaxf(p0, p1);
    float e0 = expf(p0 - m), e1 = expf(p1 - m);
    float s = e0 + e1;
    att0[gid] = e0 / s;
    att1[gid] = e1 / s;
}

// ---------------------------------------------------------------------------
__global__ __launch_bounds__(256)
void final_ht1_k(const float* __restrict__ outp, const float* __restrict__ wf,
                 const float* __restrict__ fbias, const float* __restrict__ w1,
                 const float* __restrict__ b1, const float* __restrict__ bn1,
                 float* __restrict__ o1, float* __restrict__ h0)
{
    int gid = blockIdx.x * 256 + threadIdx.x;
    int b = gid >> 14; int sp = gid & 16383;
    const float* base = outp + (((size_t)b * 256) << 14) + sp;
    float acc = 0.f;
#pragma unroll 8
    for (int c = 0; c < 256; ++c)
        acc = fmaf(wf[c], base[(size_t)c << 14], acc);
    acc += fbias[0];
    o1[gid] = acc;
    float t1 = fmaf(w1[0], acc, b1[0]);
    float inv = bn1[0] / sqrtf(bn1[3] + EPS);
    float sh  = fmaf(-bn1[2], inv, bn1[1]);
    float v = fmaf(t1, inv, sh);
    h0[gid] = fmaxf(v, 0.f);
}

// ---------------------------------------------------------------------------
__global__ __launch_bounds__(256)
void dht_k(const float* __restrict__ h0, float* __restrict__ hacc)
{
    __shared__ double cA[128], sA[128];
    __shared__ float bins[32];
    const int t = threadIdx.x;
    const int a = blockIdx.x & 127;
    const int b = blockIdx.x >> 7;
    const double irho = 182.0 / 31.0;
    if (t < 128) {
        double th = (double)a * (M_PI / 128.0);
        cA[t] = cos(th) * (double)(t - 64);
        sA[t] = sin(th) * (double)(t - 64);
    }
    if (t < 32) bins[t] = 0.f;
    __syncthreads();
    const float* hb = h0 + ((size_t)b << 14);
    for (int i = t; i < 16384; i += 256) {
        int yy = i >> 7, xx = i & 127;
        double r = (cA[xx] + sA[yy]) / irho;
        int idx = __double2int_rn(r) + 16;
        idx = idx < 0 ? 0 : (idx > 31 ? 31 : idx);
        atomicAdd(&bins[idx], hb[i]);
    }
    __syncthreads();
    if (t < 32) hacc[(size_t)blockIdx.x * 32 + t] = bins[t];
}

// ---------------------------------------------------------------------------
__global__ __launch_bounds__(256)
void htconv_k(const float* __restrict__ inp, const float* __restrict__ w9,
              const float* __restrict__ bias, const float* __restrict__ bn,
              float* __restrict__ outp)
{
    __shared__ float tile[130 * 34];
    const int t = threadIdx.x;
    const int b = blockIdx.x;
    const float* ib = inp + b * 4096;
    for (int i = t; i < 130 * 34; i += 256) {
        int ya = i / 34 - 1; int xr = i % 34 - 1;
        float v = 0.f;
        if ((unsigned)ya < 128u && (unsigned)xr < 32u) v = ib[ya * 32 + xr];
        tile[i] = v;
    }
    __syncthreads();
    float w[9];
#pragma unroll
    for (int k = 0; k < 9; ++k) w[k] = w9[k];
    const float bs = bias[0];
    const float inv = bn[0] / sqrtf(bn[3] + EPS);
    const float sh  = fmaf(-bn[2], inv, bn[1]);
    for (int i = t; i < 4096; i += 256) {
        int ya = i >> 5, xr = i & 31;
        const float* tp = &tile[ya * 34 + xr];
        float acc = bs;
#pragma unroll
        for (int ky = 0; ky < 3; ++ky)
#pragma unroll
            for (int kx = 0; kx < 3; ++kx)
                acc = fmaf(w[ky * 3 + kx], tp[ky * 34 + kx], acc);
        float v = fmaf(acc, inv, sh);
        outp[b * 4096 + i] = fmaxf(v, 0.f);
    }
}

// ---------------------------------------------------------------------------
extern "C" void kernel_launch(void* const* d_in, const int* in_sizes, int n_in,
                              void* d_out, int out_size, void* d_ws, size_t ws_size,
                              hipStream_t stream)
{
    const float* x        = (const float*)d_in[0];
    const float* conv1_w  = (const float*)d_in[1];
    const float* conv1_bn = (const float*)d_in[2];
    const float* conv1_a  = (const float*)d_in[3];
    const float* conv2_w  = (const float*)d_in[4];
    const float* conv2_bn = (const float*)d_in[5];
    const float* conv2_a  = (const float*)d_in[6];
    const float* bnr_bn   = (const float*)d_in[7];
    const float* bnr_a    = (const float*)d_in[8];
    const float* cat_w    = (const float*)d_in[9];
    const float* cat_bn   = (const float*)d_in[10];
    const float* cat_a    = (const float*)d_in[11];
    const float* attc_w   = (const float*)d_in[12];
    const float* attc_bn  = (const float*)d_in[13];
    const float* attc_a   = (const float*)d_in[14];
    const float* smooth_w = (const float*)d_in[15];
    const float* smooth_bn= (const float*)d_in[16];
    const float* smooth_a = (const float*)d_in[17];
    const float* final_w  = (const float*)d_in[18];
    const float* final_b  = (const float*)d_in[19];
    const float* ht1_w    = (const float*)d_in[20];
    const float* ht1_b    = (const float*)d_in[21];
    const float* ht1_bn   = (const float*)d_in[22];
    const float* ht2_w    = (const float*)d_in[23];
    const float* ht2_b    = (const float*)d_in[24];
    const float* ht2_bn   = (const float*)d_in[25];
    const float* ht3_w    = (const float*)d_in[26];
    const float* ht3_b    = (const float*)d_in[27];
    const float* ht3_bn   = (const float*)d_in[28];

    float* out  = (float*)d_out;                 // [4,256,128,128]
    float* o1   = out + 16777216;                // [4,1,128,128]
    float* hout = o1 + 65536;                    // [4,1,128,32]

    float* ws   = (float*)d_ws;
    float* fore = ws;                            // 16,777,216 f
    float* back = ws + 16777216;                 // 16,777,216 f
    float* x12  = ws + 2 * 16777216;             // 16,777,216 f (alive post-conv only)
    float* att0 = ws + 3 * 16777216;
    float* att1 = att0 + 65536;
    float* h0   = att1 + 65536;
    float* hacc = h0 + 65536;
    float* h2   = hacc + 16384;
    // 1x1 weight staging (must survive until gemm1) — tail region past h2:
    _Float16* wpc = (_Float16*)(ws + 3 * 16777216 + 262144);   // cat:   262,144 f16
    _Float16* wps = wpc + 262144;                              // smooth:131,072 f16

    // conv-phase scratch aliased into x12's region (dead until gemm1x1<0>):
    _Float16* xp  = (_Float16*)(ws + 2 * 16777216);              // half-batch xp
    _Float16* wpq = (_Float16*)(ws + 2 * 16777216 + 8388608);    // 3x3 weights
    _Float16* zer = (_Float16*)(ws + 2 * 16777216 + 8388608 + 1179648); // zero row
    const size_t WPC = (size_t)9 * 8 * 2 * 2 * 4096;             // per-conv wp stride

    prep_w_k<<<4608, 256, 0, stream>>>(conv1_w, conv2_w, wpq, zer);
    prep_w1x1_k<<<512, 256, 0, stream>>>(cat_w, wpc, 512);
    prep_w1x1_k<<<256, 256, 0, stream>>>(smooth_w, wps, 256);
    for (int half = 0; half < 2; ++half) {
        prep_x_k<<<256, 256, 0, stream>>>(x, xp, half * 2);
        conv3x3_mfma<0><<<512, 256, 0, stream>>>(xp, wpq, conv1_bn, conv1_a,
                                                 nullptr, nullptr, zer, fore, half * 2);
        conv3x3_mfma<1><<<512, 256, 0, stream>>>(xp, wpq + WPC, conv2_bn, conv2_a,
                                                 bnr_bn, bnr_a, zer, back, half * 2);
    }
    gemm1x1_mfma<0><<<1024, 256, 0, stream>>>(fore, back, nullptr, nullptr,
                                              wpc, cat_bn, cat_a, x12);
    attc_k<<<256, 256, 0, stream>>>(x12, attc_w, attc_bn, attc_a, att0, att1);
    gemm1x1_mfma<1><<<1024, 256, 0, stream>>>(fore, back, att0, att1,
                                              wps, smooth_bn, smooth_a, out);
    final_ht1_k<<<256, 256, 0, stream>>>(out, final_w, final_b,
                                         ht1_w, ht1_b, ht1_bn, o1, h0);
    dht_k<<<512, 256, 0, stream>>>(h0, hacc);
    htconv_k<<<4, 256, 0, stream>>>(hacc, ht2_w, ht2_b, ht2_bn, h2);
    htconv_k<<<4, 256, 0, stream>>>(h2, ht3_w, ht3_b, ht3_bn, hout);
}